// Round 1
// baseline (2936.576 us; speedup 1.0000x reference)
//
#include <hip/hip_runtime.h>
#include <hip/hip_cooperative_groups.h>
#include <stdint.h>
#include <math.h>

// Problem constants (fixed by the reference: B=8, C=8, H=512, W=512, STEPS=10)
constexpr int Wd = 512;
constexpr int Hd = 512;
constexpr int Cd = 8;
constexpr int Bd = 8;
constexpr int HW = Hd * Wd;        // 262144 = 2^18
constexpr int CHW = Cd * HW;       // 2097152
constexpr int BCHW = Bd * CHW;     // 16777216
constexpr int BHW = Bd * HW;       // 2097152 (= bytes per uint8 label field)
constexpr int NT = 256;

constexpr float LN2 = 0.69314718055994530942f;

// Natural log via the HW log2 instruction (v_log_f32, <=1 ulp) + 1 multiply.
__device__ __forceinline__ float fast_ln(float x) {
  return __builtin_amdgcn_logf(x) * LN2;
}

// Threefry-2x32, 20 rounds — bit-exact replica of JAX's threefry2x32 cipher.
__host__ __device__ __forceinline__ void tf2x32(uint32_t k0, uint32_t k1,
                                                uint32_t x0, uint32_t x1,
                                                uint32_t& o0, uint32_t& o1) {
  const uint32_t k2 = k0 ^ k1 ^ 0x1BD11BDAu;
  x0 += k0; x1 += k1;
#define TFR(r) { x0 += x1; x1 = (x1 << (r)) | (x1 >> (32 - (r))); x1 ^= x0; }
  TFR(13) TFR(15) TFR(26) TFR(6)
  x0 += k1; x1 += k2 + 1u;
  TFR(17) TFR(29) TFR(16) TFR(24)
  x0 += k2; x1 += k0 + 2u;
  TFR(13) TFR(15) TFR(26) TFR(6)
  x0 += k0; x1 += k1 + 3u;
  TFR(17) TFR(29) TFR(16) TFR(24)
  x0 += k1; x1 += k2 + 4u;
  TFR(13) TFR(15) TFR(26) TFR(6)
  x0 += k2; x1 += k0 + 5u;
#undef TFR
  o0 = x0; o1 = x1;
}

// ---------- legacy zero-slot table (kept for the gibbs_step fallback) ------
__device__ __forceinline__ void fill_sb(float* sb, const float* binaries) {
  for (int i = threadIdx.x; i < 288; i += NT) {
    const int n = i / 72, rem = i - n * 72;
    const int ch = rem / 9, nb = rem - ch * 9;
    sb[i] = (nb < 8) ? binaries[n * 64 + ch * 8 + nb] : 0.0f;
  }
}

__device__ __forceinline__ void energies(const float* __restrict__ u,
                                         const float* sb, int i0, int i1,
                                         int i2, int i3, float* e) {
#pragma unroll
  for (int ch = 0; ch < 8; ++ch) {
    float v = u[ch];
    v += sb[      ch * 9 + i0];
    v += sb[ 72 + ch * 9 + i1];
    v += sb[144 + ch * 9 + i2];
    v += sb[216 + ch * 9 + i3];
    e[ch] = v;
  }
}

// ---------- transposed table: sbT[n][nb][ch], row padded to 12 floats -----
// Reads become 2x ds_read_b128 per neighbor (8 b128 vs 32 b32 per energies
// call). Row stride 48 B: bank index (12*i + c) % 32 collides only for
// i=0 vs i=8 (2-way, free per m136). Values and FP add order are IDENTICAL
// to the legacy path -> bit-exact energies.
__device__ __forceinline__ void fill_sbT(float* sbT, const float* binaries) {
  for (int i = threadIdx.x; i < 288; i += NT) {
    const int n = i / 72, rem = i - n * 72;
    const int ch = rem / 9, nb = rem - ch * 9;
    sbT[n * 108 + nb * 12 + ch] = (nb < 8) ? binaries[n * 64 + ch * 8 + nb]
                                           : 0.0f;
  }
}

__device__ __forceinline__ void energiesT(const float* __restrict__ u,
                                          const float* sbT, int i0, int i1,
                                          int i2, int i3, float* e) {
  const float4* r0 = (const float4*)(sbT +       i0 * 12);
  const float4* r1 = (const float4*)(sbT + 108 + i1 * 12);
  const float4* r2 = (const float4*)(sbT + 216 + i2 * 12);
  const float4* r3 = (const float4*)(sbT + 324 + i3 * 12);
  const float4 a0 = r0[0], b0 = r0[1];
  const float4 a1 = r1[0], b1 = r1[1];
  const float4 a2 = r2[0], b2 = r2[1];
  const float4 a3 = r3[0], b3 = r3[1];
  // Same left-assoc order as reference: ((((u + n0) + n1) + n2) + n3)
  e[0] = u[0] + a0.x + a1.x + a2.x + a3.x;
  e[1] = u[1] + a0.y + a1.y + a2.y + a3.y;
  e[2] = u[2] + a0.z + a1.z + a2.z + a3.z;
  e[3] = u[3] + a0.w + a1.w + a2.w + a3.w;
  e[4] = u[4] + b0.x + b1.x + b2.x + b3.x;
  e[5] = u[5] + b0.y + b1.y + b2.y + b3.y;
  e[6] = u[6] + b0.z + b1.z + b2.z + b3.z;
  e[7] = u[7] + b0.w + b1.w + b2.w + b3.w;
}

// Gumbel-argmax over 8 classes. Partitionable threefry: bits[j] = y0^y1 of
// cipher(key_t, (0, j)), j = flat index into (B,C,H,W); j = ub + ch*HW here.
__device__ __forceinline__ int gumbel_argmax(const float* e, int ub,
                                             uint32_t k0, uint32_t k1) {
  float zbest = 0.0f;
  int amax = 0;
#pragma unroll
  for (int ch = 0; ch < 8; ++ch) {
    uint32_t y0, y1;
    tf2x32(k0, k1, 0u, (uint32_t)(ub + ch * HW), y0, y1);
    const uint32_t bits = y0 ^ y1;
    const float f = __uint_as_float((bits >> 9) | 0x3F800000u) - 1.0f;
    const float U = (f > 0.0f) ? f : 1.17549435082228751e-38f;
    const float l1 = fast_ln(U);          // ln(U), HW log2 path
    const float gum = -fast_ln(-l1);      // -ln(-ln(U))
    const float z = gum - e[ch];
    if (ch == 0 || z > zbest) { zbest = z; amax = ch; }  // first-max ties
  }
  return amax;
}

struct TKeys { uint32_t a[10]; uint32_t b[10]; };

// ---------------- Cooperative fused trajectory (1 launch, 10 steps) -------
// Grid = 1024 blocks x 256 threads = 262144 threads = HW: each thread owns
// one (r,c) pixel across all B=8 images (decode/masks/LDS fill hoisted out
// of the 10-step loop; 8 independent sites per thread give the scheduler
// huge ILP at 4 waves/SIMD). Labels for step t go to write-once slot
// sbufs + t*BHW (t<9) — identical layout to what prob_pass replays.
// __launch_bounds__(256, 4): VGPR <= 128 -> 16 waves/CU -> 4 blocks/CU ->
// exactly 1024 co-resident blocks, the cooperative-launch requirement.
__global__ __launch_bounds__(NT, 4) void traj_coop(
    const float* __restrict__ unaries, const float* __restrict__ binaries,
    const int* __restrict__ s0_int, uint8_t* __restrict__ sbufs,
    float* __restrict__ sfin, TKeys keys) {
  __shared__ __align__(16) float sbT[432];
  fill_sbT(sbT, binaries);
  __syncthreads();

  const int site = blockIdx.x * NT + threadIdx.x;   // 0..HW-1
  const int c = site & (Wd - 1);
  const int r = site >> 9;
  const bool v0 = (c + 1) < Wd, v1 = (r + 1) < Hd, v2 = c > 0, v3 = r > 0;

  cooperative_groups::grid_group grid = cooperative_groups::this_grid();

#pragma unroll 1
  for (int t = 0; t < 10; ++t) {
    const uint32_t k0 = keys.a[t], k1 = keys.b[t];
    const uint8_t* sprev = sbufs + (size_t)(t - 1) * BHW;  // unused at t==0
    uint8_t* sout = sbufs + (size_t)t * BHW;

#pragma unroll 1
    for (int b = 0; b < Bd; ++b) {
      const int bs = b * HW + site;
      int i0, i1, i2, i3;
      if (t == 0) {   // uniform branch (scalar)
        i0 = v0 ? s0_int[bs + 1]  : 8;
        i1 = v1 ? s0_int[bs + Wd] : 8;
        i2 = v2 ? s0_int[bs - 1]  : 8;
        i3 = v3 ? s0_int[bs - Wd] : 8;
      } else {
        i0 = v0 ? (int)sprev[bs + 1]  : 8;
        i1 = v1 ? (int)sprev[bs + Wd] : 8;
        i2 = v2 ? (int)sprev[bs - 1]  : 8;
        i3 = v3 ? (int)sprev[bs - Wd] : 8;
      }
      const int ub = b * CHW + site;
      float u[8];
#pragma unroll
      for (int ch = 0; ch < 8; ++ch) u[ch] = unaries[ub + ch * HW];
      float e[8];
      energiesT(u, sbT, i0, i1, i2, i3, e);

      const int amax = gumbel_argmax(e, ub, k0, k1);

      if (t == 9) sfin[bs] = (float)amax;       // final labels as f32
      else        sout[bs] = (uint8_t)amax;
    }

    if (t < 9) {
      // agent-scope fence (L2 WB+INV on gfx950) around the grid barrier:
      // labels written on one XCD must be visible to readers on others,
      // and reader L2s must drop lines cached from prior graph executions.
      __threadfence();
      grid.sync();
      __threadfence();
    }
  }
}

// ---------------- Pass 1 fallback: trajectory, 10 launches ----------------
template <int FIRST, int LAST>
__global__ __launch_bounds__(NT) void traj_step(
    const float* __restrict__ unaries, const float* __restrict__ binaries,
    const int* __restrict__ s0_int, const uint8_t* __restrict__ s_in,
    uint8_t* __restrict__ s_out, float* __restrict__ sfin,
    uint32_t k0, uint32_t k1) {
  __shared__ __align__(16) float sbT[432];
  fill_sbT(sbT, binaries);
  __syncthreads();

  const int tid = blockIdx.x * NT + threadIdx.x;  // flat (b, r, c)
  const int c = tid & (Wd - 1);
  const int r = (tid >> 9) & (Hd - 1);
  const int b = tid >> 18;
  const int site = tid & (HW - 1);

  int i0, i1, i2, i3;
  if (FIRST) {
    i0 = (c + 1) < Wd ? s0_int[tid + 1]  : 8;
    i1 = (r + 1) < Hd ? s0_int[tid + Wd] : 8;
    i2 = c > 0        ? s0_int[tid - 1]  : 8;
    i3 = r > 0        ? s0_int[tid - Wd] : 8;
  } else {
    i0 = (c + 1) < Wd ? (int)s_in[tid + 1]  : 8;
    i1 = (r + 1) < Hd ? (int)s_in[tid + Wd] : 8;
    i2 = c > 0        ? (int)s_in[tid - 1]  : 8;
    i3 = r > 0        ? (int)s_in[tid - Wd] : 8;
  }

  const int ub = b * CHW + site;
  float u[8];
#pragma unroll
  for (int ch = 0; ch < 8; ++ch) u[ch] = unaries[ub + ch * HW];
  float e[8];
  energiesT(u, sbT, i0, i1, i2, i3, e);

  const int amax = gumbel_argmax(e, ub, k0, k1);

  if (LAST) sfin[tid] = (float)amax;
  else      s_out[tid] = (uint8_t)amax;
}

// ---------------- Pass 2: marginals only (1 launch) ----------------
__global__ __launch_bounds__(NT) void prob_pass(
    const float* __restrict__ unaries, const float* __restrict__ binaries,
    const int* __restrict__ s0_int, const uint8_t* __restrict__ sbufs,
    float* __restrict__ acc_out) {
  __shared__ __align__(16) float sbT[432];
  fill_sbT(sbT, binaries);
  __syncthreads();

  const int tid = blockIdx.x * NT + threadIdx.x;
  const int c = tid & (Wd - 1);
  const int r = (tid >> 9) & (Hd - 1);
  const int b = tid >> 18;
  const int site = tid & (HW - 1);
  const bool v0 = (c + 1) < Wd, v1 = (r + 1) < Hd, v2 = c > 0, v3 = r > 0;

  const int ub = b * CHW + site;
  float u[8];
#pragma unroll
  for (int ch = 0; ch < 8; ++ch) u[ch] = unaries[ub + ch * HW];

  float acc[8] = {};

#pragma unroll 1
  for (int t = 0; t < 10; ++t) {
    int i0, i1, i2, i3;
    if (t == 0) {
      i0 = v0 ? s0_int[tid + 1]  : 8;
      i1 = v1 ? s0_int[tid + Wd] : 8;
      i2 = v2 ? s0_int[tid - 1]  : 8;
      i3 = v3 ? s0_int[tid - Wd] : 8;
    } else {
      const uint8_t* s = sbufs + (size_t)(t - 1) * BHW;
      i0 = v0 ? (int)s[tid + 1]  : 8;
      i1 = v1 ? (int)s[tid + Wd] : 8;
      i2 = v2 ? (int)s[tid - 1]  : 8;
      i3 = v3 ? (int)s[tid - Wd] : 8;
    }

    float e[8];
    energiesT(u, sbT, i0, i1, i2, i3, e);

    float m = -e[0];
#pragma unroll
    for (int ch = 1; ch < 8; ++ch) m = fmaxf(m, -e[ch]);
    float p[8];
    float s = 0.0f;
#pragma unroll
    for (int ch = 0; ch < 8; ++ch) { p[ch] = __expf(-e[ch] - m); s += p[ch]; }
    const float inv = __builtin_amdgcn_rcpf(s);   // 1-ulp HW reciprocal
#pragma unroll
    for (int ch = 0; ch < 8; ++ch) acc[ch] += p[ch] * inv;
  }

#pragma unroll
  for (int ch = 0; ch < 8; ++ch) acc_out[ub + ch * HW] = acc[ch] * 0.1f;
}

// ---------------- Fallback: round-2 structure (proven, ws < 9*BHW) --------
__global__ __launch_bounds__(NT) void gibbs_step(
    const float* __restrict__ unaries, const float* __restrict__ binaries,
    const int* __restrict__ s_in, int* __restrict__ s_out,
    float* __restrict__ acc, float* __restrict__ sfin,
    uint32_t k0, uint32_t k1, int mode) {
  __shared__ float sb[288];
  fill_sb(sb, binaries);
  __syncthreads();

  const int tid = blockIdx.x * NT + threadIdx.x;
  const int c = tid & (Wd - 1);
  const int r = (tid >> 9) & (Hd - 1);
  const int b = tid >> 18;
  const int i0 = (c + 1) < Wd ? s_in[tid + 1]  : 8;
  const int i1 = (r + 1) < Hd ? s_in[tid + Wd] : 8;
  const int i2 = c > 0        ? s_in[tid - 1]  : 8;
  const int i3 = r > 0        ? s_in[tid - Wd] : 8;

  const int ub = b * CHW + (tid & (HW - 1));
  float u[8];
#pragma unroll
  for (int ch = 0; ch < 8; ++ch) u[ch] = unaries[ub + ch * HW];
  float e[8];
  energies(u, sb, i0, i1, i2, i3, e);

  const int amax = gumbel_argmax(e, ub, k0, k1);

  float m = -e[0];
#pragma unroll
  for (int ch = 1; ch < 8; ++ch) m = fmaxf(m, -e[ch]);
  float p[8];
  float s = 0.0f;
#pragma unroll
  for (int ch = 0; ch < 8; ++ch) { p[ch] = __expf(-e[ch] - m); s += p[ch]; }
  const float inv = __builtin_amdgcn_rcpf(s);

  if (mode == 0) {
#pragma unroll
    for (int ch = 0; ch < 8; ++ch) acc[ub + ch * HW] = p[ch] * inv;
  } else if (mode == 1) {
#pragma unroll
    for (int ch = 0; ch < 8; ++ch) acc[ub + ch * HW] += p[ch] * inv;
  } else {
#pragma unroll
    for (int ch = 0; ch < 8; ++ch) {
      const int ix = ub + ch * HW;
      acc[ix] = (acc[ix] + p[ch] * inv) * 0.1f;
    }
  }

  if (mode != 2) s_out[tid] = amax;
  else sfin[tid] = (float)amax;
}

extern "C" void kernel_launch(void* const* d_in, const int* in_sizes, int n_in,
                              void* d_out, int out_size, void* d_ws, size_t ws_size,
                              hipStream_t stream) {
  const float* unaries  = (const float*)d_in[0];
  const float* binaries = (const float*)d_in[1];
  const int*   sample0  = (const int*)d_in[2];
  // d_in[3] is sample_steps (=10, fixed by the reference) — hard-coded.

  float* acc_out = (float*)d_out;     // [B,C,H,W] marginals
  float* sfin = acc_out + BCHW;       // s_final (as floats), tail of d_out

  TKeys hk;
  for (int t = 0; t < 10; ++t)
    tf2x32(0u, 42u, 0u, (uint32_t)t, hk.a[t], hk.b[t]);  // keys[t]=split(key(42))

  const dim3 grid(BHW / NT), blk(NT);

  if (ws_size >= (size_t)9 * BHW) {
    uint8_t* sbufs = (uint8_t*)d_ws;

    // Preferred: one cooperative kernel for all 10 trajectory steps.
    void* kargs[] = {(void*)&unaries, (void*)&binaries, (void*)&sample0,
                     (void*)&sbufs, (void*)&sfin, (void*)&hk};
    hipError_t cerr = hipLaunchCooperativeKernel(
        (const void*)traj_coop, dim3(HW / NT), dim3(NT), kargs, 0, stream);

    if (cerr != hipSuccess) {
      (void)hipGetLastError();   // clear error state; fall back (proven path)
      for (int t = 0; t < 10; ++t) {
        const uint8_t* sin = (t == 0) ? nullptr : sbufs + (size_t)(t - 1) * BHW;
        uint8_t* sout = (t == 9) ? nullptr : sbufs + (size_t)t * BHW;
        if (t == 0)
          traj_step<1, 0><<<grid, blk, 0, stream>>>(unaries, binaries, sample0,
                                                    nullptr, sout, sfin,
                                                    hk.a[t], hk.b[t]);
        else if (t == 9)
          traj_step<0, 1><<<grid, blk, 0, stream>>>(unaries, binaries, nullptr,
                                                    sin, nullptr, sfin,
                                                    hk.a[t], hk.b[t]);
        else
          traj_step<0, 0><<<grid, blk, 0, stream>>>(unaries, binaries, nullptr,
                                                    sin, sout, sfin,
                                                    hk.a[t], hk.b[t]);
      }
    }
    prob_pass<<<grid, blk, 0, stream>>>(unaries, binaries, sample0, sbufs,
                                        acc_out);
  } else {
    // Fallback (proven in r1/r2): per-step fused kernels, int32 ping-pong.
    int* bufA = (int*)d_ws;
    int* bufB = (int*)sfin;
    for (int t = 0; t < 10; ++t) {
      const int* sin = (t == 0) ? sample0 : ((t & 1) ? bufA : bufB);
      int* sout = (t & 1) ? bufB : bufA;
      const int mode = (t == 0) ? 0 : ((t == 9) ? 2 : 1);
      gibbs_step<<<grid, blk, 0, stream>>>(unaries, binaries, sin, sout,
                                           acc_out, sfin, hk.a[t], hk.b[t], mode);
    }
  }
}

// Round 2
// 719.296 us; speedup vs baseline: 4.0826x; 4.0826x over previous
//
#include <hip/hip_runtime.h>
#include <stdint.h>
#include <math.h>

// Problem constants (fixed by the reference: B=8, C=8, H=512, W=512, STEPS=10)
constexpr int Wd = 512;
constexpr int Hd = 512;
constexpr int Cd = 8;
constexpr int Bd = 8;
constexpr int HW = Hd * Wd;        // 262144 = 2^18
constexpr int CHW = Cd * HW;       // 2097152
constexpr int BCHW = Bd * CHW;     // 16777216
constexpr int BHW = Bd * HW;       // 2097152 (= bytes per uint8 label field)
constexpr int NT = 256;

// Fused-trajectory tiling: 16x64 interior, 18x66 extended (halo=1).
constexpr int TR = 16, TC = 64;          // interior tile
constexpr int ER = TR + 2, EC = TC + 2;  // extended tile
constexpr int ESZ = ER * EC;             // 1188 sites
constexpr int TILES = (Hd / TR) * (Wd / TC);  // 256 tiles per image

constexpr float LN2 = 0.69314718055994530942f;

// Natural log via the HW log2 instruction (v_log_f32, <=1 ulp) + 1 multiply.
__device__ __forceinline__ float fast_ln(float x) {
  return __builtin_amdgcn_logf(x) * LN2;
}

// Threefry-2x32, 20 rounds — bit-exact replica of JAX's threefry2x32 cipher.
__host__ __device__ __forceinline__ void tf2x32(uint32_t k0, uint32_t k1,
                                                uint32_t x0, uint32_t x1,
                                                uint32_t& o0, uint32_t& o1) {
  const uint32_t k2 = k0 ^ k1 ^ 0x1BD11BDAu;
  x0 += k0; x1 += k1;
#define TFR(r) { x0 += x1; x1 = (x1 << (r)) | (x1 >> (32 - (r))); x1 ^= x0; }
  TFR(13) TFR(15) TFR(26) TFR(6)
  x0 += k1; x1 += k2 + 1u;
  TFR(17) TFR(29) TFR(16) TFR(24)
  x0 += k2; x1 += k0 + 2u;
  TFR(13) TFR(15) TFR(26) TFR(6)
  x0 += k0; x1 += k1 + 3u;
  TFR(17) TFR(29) TFR(16) TFR(24)
  x0 += k1; x1 += k2 + 4u;
  TFR(13) TFR(15) TFR(26) TFR(6)
  x0 += k2; x1 += k0 + 5u;
#undef TFR
  o0 = x0; o1 = x1;
}

// ---------- legacy zero-slot table (kept for the gibbs_step fallback) ------
__device__ __forceinline__ void fill_sb(float* sb, const float* binaries) {
  for (int i = threadIdx.x; i < 288; i += NT) {
    const int n = i / 72, rem = i - n * 72;
    const int ch = rem / 9, nb = rem - ch * 9;
    sb[i] = (nb < 8) ? binaries[n * 64 + ch * 8 + nb] : 0.0f;
  }
}

__device__ __forceinline__ void energies(const float* __restrict__ u,
                                         const float* sb, int i0, int i1,
                                         int i2, int i3, float* e) {
#pragma unroll
  for (int ch = 0; ch < 8; ++ch) {
    float v = u[ch];
    v += sb[      ch * 9 + i0];
    v += sb[ 72 + ch * 9 + i1];
    v += sb[144 + ch * 9 + i2];
    v += sb[216 + ch * 9 + i3];
    e[ch] = v;
  }
}

// ---------- transposed table: sbT[n][nb][ch], row padded to 12 floats -----
// Reads are 2x ds_read_b128 per neighbor (8 b128 vs 32 b32 per energies).
// Row stride 48 B: worst aliasing is 2-way (free per m136). Values and FP
// add order IDENTICAL to the legacy path -> bit-exact energies.
__device__ __forceinline__ void fill_sbT(float* sbT, const float* binaries) {
  for (int i = threadIdx.x; i < 288; i += NT) {
    const int n = i / 72, rem = i - n * 72;
    const int ch = rem / 9, nb = rem - ch * 9;
    sbT[n * 108 + nb * 12 + ch] = (nb < 8) ? binaries[n * 64 + ch * 8 + nb]
                                           : 0.0f;
  }
}

__device__ __forceinline__ void energiesT(const float* __restrict__ u,
                                          const float* sbT, int i0, int i1,
                                          int i2, int i3, float* e) {
  const float4* r0 = (const float4*)(sbT +       i0 * 12);
  const float4* r1 = (const float4*)(sbT + 108 + i1 * 12);
  const float4* r2 = (const float4*)(sbT + 216 + i2 * 12);
  const float4* r3 = (const float4*)(sbT + 324 + i3 * 12);
  const float4 a0 = r0[0], b0 = r0[1];
  const float4 a1 = r1[0], b1 = r1[1];
  const float4 a2 = r2[0], b2 = r2[1];
  const float4 a3 = r3[0], b3 = r3[1];
  // Same left-assoc order as reference: ((((u + n0) + n1) + n2) + n3)
  e[0] = u[0] + a0.x + a1.x + a2.x + a3.x;
  e[1] = u[1] + a0.y + a1.y + a2.y + a3.y;
  e[2] = u[2] + a0.z + a1.z + a2.z + a3.z;
  e[3] = u[3] + a0.w + a1.w + a2.w + a3.w;
  e[4] = u[4] + b0.x + b1.x + b2.x + b3.x;
  e[5] = u[5] + b0.y + b1.y + b2.y + b3.y;
  e[6] = u[6] + b0.z + b1.z + b2.z + b3.z;
  e[7] = u[7] + b0.w + b1.w + b2.w + b3.w;
}

// Gumbel-argmax over 8 classes. Partitionable threefry: bits[j] = y0^y1 of
// cipher(key_t, (0, j)), j = flat index into (B,C,H,W); j = ub + ch*HW here.
__device__ __forceinline__ int gumbel_argmax(const float* e, int ub,
                                             uint32_t k0, uint32_t k1) {
  float zbest = 0.0f;
  int amax = 0;
#pragma unroll
  for (int ch = 0; ch < 8; ++ch) {
    uint32_t y0, y1;
    tf2x32(k0, k1, 0u, (uint32_t)(ub + ch * HW), y0, y1);
    const uint32_t bits = y0 ^ y1;
    const float f = __uint_as_float((bits >> 9) | 0x3F800000u) - 1.0f;
    const float U = (f > 0.0f) ? f : 1.17549435082228751e-38f;
    const float l1 = fast_ln(U);          // ln(U), HW log2 path
    const float gum = -fast_ln(-l1);      // -ln(-ln(U))
    const float z = gum - e[ch];
    if (ch == 0 || z > zbest) { zbest = z; amax = ch; }  // first-max ties
  }
  return amax;
}

// ------------- Fused trajectory: 2 Gibbs steps per launch (halo=1) --------
// Block = one (image b, 16x64 tile). Phase A: step t over the 18x66
// extended tile (halo sites recomputed redundantly by neighbor blocks —
// bit-identical, deterministic). Labels -> LDS (+ interior -> global).
// __syncthreads(). Phase B: step t+1 over the 16x64 interior, neighbors
// from LDS. 5 launches replace 10; no grid-wide sync, no fences.
// VALU overhead: +1188/1024 on phase A only ~= +8% total.
template <int FIRST, int LAST>
__global__ __launch_bounds__(NT, 8) void traj_fused(
    const float* __restrict__ unaries, const float* __restrict__ binaries,
    const int* __restrict__ s0_int, const uint8_t* __restrict__ sprev,
    uint8_t* __restrict__ soutA, uint8_t* __restrict__ soutB,
    float* __restrict__ sfin,
    uint32_t k0a, uint32_t k1a, uint32_t k0b, uint32_t k1b) {
  __shared__ __align__(16) float sbT[432];
  __shared__ uint8_t lab[ESZ];
  fill_sbT(sbT, binaries);
  __syncthreads();

  const int b    = blockIdx.x >> 8;          // 256 tiles per image
  const int tile = blockIdx.x & 255;
  const int tr   = (tile >> 3) << 4;         // (tile/8)*16
  const int tc   = (tile & 7) << 6;          // (tile%8)*64
  const int base = b * HW;

  // ---- Phase A: step t over extended region ----
#pragma unroll 1
  for (int k = 0; k < 5; ++k) {
    const int s = threadIdx.x + k * NT;
    if (s < ESZ) {
      const int er = s / EC, ec = s - er * EC;
      const int r = tr + er - 1, c = tc + ec - 1;
      if ((unsigned)r < (unsigned)Hd && (unsigned)c < (unsigned)Wd) {
        const int g = base + (r << 9) + c;
        int i0, i1, i2, i3;
        if (FIRST) {
          i0 = (c + 1) < Wd ? s0_int[g + 1]  : 8;
          i1 = (r + 1) < Hd ? s0_int[g + Wd] : 8;
          i2 = c > 0        ? s0_int[g - 1]  : 8;
          i3 = r > 0        ? s0_int[g - Wd] : 8;
        } else {
          i0 = (c + 1) < Wd ? (int)sprev[g + 1]  : 8;
          i1 = (r + 1) < Hd ? (int)sprev[g + Wd] : 8;
          i2 = c > 0        ? (int)sprev[g - 1]  : 8;
          i3 = r > 0        ? (int)sprev[g - Wd] : 8;
        }
        const int ub = b * CHW + (r << 9) + c;
        float u[8];
#pragma unroll
        for (int ch = 0; ch < 8; ++ch) u[ch] = unaries[ub + ch * HW];
        float e[8];
        energiesT(u, sbT, i0, i1, i2, i3, e);
        const int amax = gumbel_argmax(e, ub, k0a, k1a);
        lab[s] = (uint8_t)amax;
        // interior sites are owned by this block: persist step-t label
        if (er >= 1 && er < (ER - 1) && ec >= 1 && ec < (EC - 1))
          soutA[g] = (uint8_t)amax;
      }
    }
  }
  __syncthreads();

  // ---- Phase B: step t+1 over interior, neighbors from LDS ----
#pragma unroll 1
  for (int k = 0; k < 4; ++k) {
    const int s = threadIdx.x + k * NT;      // 0..1023
    const int ir = s >> 6, ic = s & 63;
    const int er = ir + 1, ec = ic + 1;
    const int r = tr + ir, c = tc + ic;
    const int g = base + (r << 9) + c;
    const int ls = er * EC + ec;
    const int i0 = (c + 1) < Wd ? (int)lab[ls + 1]  : 8;
    const int i1 = (r + 1) < Hd ? (int)lab[ls + EC] : 8;
    const int i2 = c > 0        ? (int)lab[ls - 1]  : 8;
    const int i3 = r > 0        ? (int)lab[ls - EC] : 8;
    const int ub = b * CHW + (r << 9) + c;
    float u[8];
#pragma unroll
    for (int ch = 0; ch < 8; ++ch) u[ch] = unaries[ub + ch * HW];
    float e[8];
    energiesT(u, sbT, i0, i1, i2, i3, e);
    const int amax = gumbel_argmax(e, ub, k0b, k1b);
    if (LAST) sfin[g] = (float)amax;         // final labels as f32
    else      soutB[g] = (uint8_t)amax;
  }
}

// ---------------- Pass 2: marginals only (1 launch) ----------------
__global__ __launch_bounds__(NT) void prob_pass(
    const float* __restrict__ unaries, const float* __restrict__ binaries,
    const int* __restrict__ s0_int, const uint8_t* __restrict__ sbufs,
    float* __restrict__ acc_out) {
  __shared__ __align__(16) float sbT[432];
  fill_sbT(sbT, binaries);
  __syncthreads();

  const int tid = blockIdx.x * NT + threadIdx.x;
  const int c = tid & (Wd - 1);
  const int r = (tid >> 9) & (Hd - 1);
  const int b = tid >> 18;
  const int site = tid & (HW - 1);
  const bool v0 = (c + 1) < Wd, v1 = (r + 1) < Hd, v2 = c > 0, v3 = r > 0;

  const int ub = b * CHW + site;
  float u[8];
#pragma unroll
  for (int ch = 0; ch < 8; ++ch) u[ch] = unaries[ub + ch * HW];

  float acc[8] = {};

#pragma unroll 1
  for (int t = 0; t < 10; ++t) {
    int i0, i1, i2, i3;
    if (t == 0) {
      i0 = v0 ? s0_int[tid + 1]  : 8;
      i1 = v1 ? s0_int[tid + Wd] : 8;
      i2 = v2 ? s0_int[tid - 1]  : 8;
      i3 = v3 ? s0_int[tid - Wd] : 8;
    } else {
      const uint8_t* s = sbufs + (size_t)(t - 1) * BHW;
      i0 = v0 ? (int)s[tid + 1]  : 8;
      i1 = v1 ? (int)s[tid + Wd] : 8;
      i2 = v2 ? (int)s[tid - 1]  : 8;
      i3 = v3 ? (int)s[tid - Wd] : 8;
    }

    float e[8];
    energiesT(u, sbT, i0, i1, i2, i3, e);

    float m = -e[0];
#pragma unroll
    for (int ch = 1; ch < 8; ++ch) m = fmaxf(m, -e[ch]);
    float p[8];
    float s = 0.0f;
#pragma unroll
    for (int ch = 0; ch < 8; ++ch) { p[ch] = __expf(-e[ch] - m); s += p[ch]; }
    const float inv = __builtin_amdgcn_rcpf(s);   // 1-ulp HW reciprocal
#pragma unroll
    for (int ch = 0; ch < 8; ++ch) acc[ch] += p[ch] * inv;
  }

#pragma unroll
  for (int ch = 0; ch < 8; ++ch) acc_out[ub + ch * HW] = acc[ch] * 0.1f;
}

// ---------------- Fallback: round-2 structure (proven, ws < 9*BHW) --------
__global__ __launch_bounds__(NT) void gibbs_step(
    const float* __restrict__ unaries, const float* __restrict__ binaries,
    const int* __restrict__ s_in, int* __restrict__ s_out,
    float* __restrict__ acc, float* __restrict__ sfin,
    uint32_t k0, uint32_t k1, int mode) {
  __shared__ float sb[288];
  fill_sb(sb, binaries);
  __syncthreads();

  const int tid = blockIdx.x * NT + threadIdx.x;
  const int c = tid & (Wd - 1);
  const int r = (tid >> 9) & (Hd - 1);
  const int b = tid >> 18;
  const int i0 = (c + 1) < Wd ? s_in[tid + 1]  : 8;
  const int i1 = (r + 1) < Hd ? s_in[tid + Wd] : 8;
  const int i2 = c > 0        ? s_in[tid - 1]  : 8;
  const int i3 = r > 0        ? s_in[tid - Wd] : 8;

  const int ub = b * CHW + (tid & (HW - 1));
  float u[8];
#pragma unroll
  for (int ch = 0; ch < 8; ++ch) u[ch] = unaries[ub + ch * HW];
  float e[8];
  energies(u, sb, i0, i1, i2, i3, e);

  const int amax = gumbel_argmax(e, ub, k0, k1);

  float m = -e[0];
#pragma unroll
  for (int ch = 1; ch < 8; ++ch) m = fmaxf(m, -e[ch]);
  float p[8];
  float s = 0.0f;
#pragma unroll
  for (int ch = 0; ch < 8; ++ch) { p[ch] = __expf(-e[ch] - m); s += p[ch]; }
  const float inv = __builtin_amdgcn_rcpf(s);

  if (mode == 0) {
#pragma unroll
    for (int ch = 0; ch < 8; ++ch) acc[ub + ch * HW] = p[ch] * inv;
  } else if (mode == 1) {
#pragma unroll
    for (int ch = 0; ch < 8; ++ch) acc[ub + ch * HW] += p[ch] * inv;
  } else {
#pragma unroll
    for (int ch = 0; ch < 8; ++ch) {
      const int ix = ub + ch * HW;
      acc[ix] = (acc[ix] + p[ch] * inv) * 0.1f;
    }
  }

  if (mode != 2) s_out[tid] = amax;
  else sfin[tid] = (float)amax;
}

extern "C" void kernel_launch(void* const* d_in, const int* in_sizes, int n_in,
                              void* d_out, int out_size, void* d_ws, size_t ws_size,
                              hipStream_t stream) {
  const float* unaries  = (const float*)d_in[0];
  const float* binaries = (const float*)d_in[1];
  const int*   sample0  = (const int*)d_in[2];
  // d_in[3] is sample_steps (=10, fixed by the reference) — hard-coded.

  float* acc_out = (float*)d_out;     // [B,C,H,W] marginals
  float* sfin = acc_out + BCHW;       // s_final (as floats), tail of d_out

  uint32_t ka[10], kb[10];
  for (int t = 0; t < 10; ++t)
    tf2x32(0u, 42u, 0u, (uint32_t)t, ka[t], kb[t]);  // keys[t]=split(key(42))

  const dim3 blk(NT);

  if (ws_size >= (size_t)9 * BHW) {
    // Two-pass: 9 uint8 label fields (s_1..s_9) live in ws for replay.
    uint8_t* sbufs = (uint8_t*)d_ws;
    const dim3 fgrid(Bd * TILES);     // 2048 blocks, 8 per CU

    for (int L = 0; L < 5; ++L) {
      const int tA = 2 * L;
      const uint8_t* sprev = (L == 0) ? nullptr
                                      : sbufs + (size_t)(tA - 1) * BHW;
      uint8_t* soutA = sbufs + (size_t)tA * BHW;
      uint8_t* soutB = (L == 4) ? nullptr : sbufs + (size_t)(tA + 1) * BHW;
      if (L == 0)
        traj_fused<1, 0><<<fgrid, blk, 0, stream>>>(
            unaries, binaries, sample0, nullptr, soutA, soutB, sfin,
            ka[tA], kb[tA], ka[tA + 1], kb[tA + 1]);
      else if (L == 4)
        traj_fused<0, 1><<<fgrid, blk, 0, stream>>>(
            unaries, binaries, nullptr, sprev, soutA, nullptr, sfin,
            ka[tA], kb[tA], ka[tA + 1], kb[tA + 1]);
      else
        traj_fused<0, 0><<<fgrid, blk, 0, stream>>>(
            unaries, binaries, nullptr, sprev, soutA, soutB, sfin,
            ka[tA], kb[tA], ka[tA + 1], kb[tA + 1]);
    }
    prob_pass<<<dim3(BHW / NT), blk, 0, stream>>>(unaries, binaries, sample0,
                                                  sbufs, acc_out);
  } else {
    // Fallback (proven in r1/r2): per-step fused kernels, int32 ping-pong.
    int* bufA = (int*)d_ws;
    int* bufB = (int*)sfin;           // pong aliases d_out tail (safe: floats
                                      // only written at t=9, which reads bufA)
    const dim3 grid(BHW / NT);
    for (int t = 0; t < 10; ++t) {
      const int* sin = (t == 0) ? sample0 : ((t & 1) ? bufA : bufB);
      int* sout = (t & 1) ? bufB : bufA;
      const int mode = (t == 0) ? 0 : ((t == 9) ? 2 : 1);
      gibbs_step<<<grid, blk, 0, stream>>>(unaries, binaries, sin, sout,
                                           acc_out, sfin, ka[t], kb[t], mode);
    }
  }
}

// Round 3
// 565.106 us; speedup vs baseline: 5.1965x; 1.2728x over previous
//
#include <hip/hip_runtime.h>
#include <stdint.h>
#include <math.h>

// Problem constants (fixed by the reference: B=8, C=8, H=512, W=512, STEPS=10)
constexpr int Wd = 512;
constexpr int Hd = 512;
constexpr int Cd = 8;
constexpr int Bd = 8;
constexpr int HW = Hd * Wd;        // 262144 = 2^18
constexpr int CHW = Cd * HW;       // 2097152
constexpr int BCHW = Bd * CHW;     // 16777216
constexpr int BHW = Bd * HW;       // 2097152 (= bytes per uint8 label field)
constexpr int NT = 256;

constexpr float LN2 = 0.69314718055994530942f;
constexpr float L2E = 1.44269504088896340736f;   // log2(e)

// Natural log via the HW log2 instruction (v_log_f32, <=1 ulp) + 1 multiply.
__device__ __forceinline__ float fast_ln(float x) {
  return __builtin_amdgcn_logf(x) * LN2;
}

// Threefry-2x32, 20 rounds — bit-exact replica of JAX's threefry2x32 cipher.
// Rotate via __builtin_rotateleft32 -> guaranteed single v_alignbit_b32
// (the (x<<r)|(x>>(32-r)) idiom MAY lower to 3 insts; at 160 rotates per
// site-step that is the single largest codegen risk).
__host__ __device__ __forceinline__ void tf2x32(uint32_t k0, uint32_t k1,
                                                uint32_t x0, uint32_t x1,
                                                uint32_t& o0, uint32_t& o1) {
  const uint32_t k2 = k0 ^ k1 ^ 0x1BD11BDAu;
  x0 += k0; x1 += k1;
#define TFR(r) { x0 += x1; x1 = __builtin_rotateleft32(x1, (r)); x1 ^= x0; }
  TFR(13) TFR(15) TFR(26) TFR(6)
  x0 += k1; x1 += k2 + 1u;
  TFR(17) TFR(29) TFR(16) TFR(24)
  x0 += k2; x1 += k0 + 2u;
  TFR(13) TFR(15) TFR(26) TFR(6)
  x0 += k0; x1 += k1 + 3u;
  TFR(17) TFR(29) TFR(16) TFR(24)
  x0 += k1; x1 += k2 + 4u;
  TFR(13) TFR(15) TFR(26) TFR(6)
  x0 += k2; x1 += k0 + 5u;
#undef TFR
  o0 = x0; o1 = x1;
}

// ---------- legacy zero-slot table (kept for the gibbs_step fallback) ------
__device__ __forceinline__ void fill_sb(float* sb, const float* binaries) {
  for (int i = threadIdx.x; i < 288; i += NT) {
    const int n = i / 72, rem = i - n * 72;
    const int ch = rem / 9, nb = rem - ch * 9;
    sb[i] = (nb < 8) ? binaries[n * 64 + ch * 8 + nb] : 0.0f;
  }
}

__device__ __forceinline__ void energies(const float* __restrict__ u,
                                         const float* sb, int i0, int i1,
                                         int i2, int i3, float* e) {
#pragma unroll
  for (int ch = 0; ch < 8; ++ch) {
    float v = u[ch];
    v += sb[      ch * 9 + i0];
    v += sb[ 72 + ch * 9 + i1];
    v += sb[144 + ch * 9 + i2];
    v += sb[216 + ch * 9 + i3];
    e[ch] = v;
  }
}

// ---------- transposed table: sbT[n][nb][ch], row padded to 12 floats -----
// Reads are 2x ds_read_b128 per neighbor (8 b128 vs 32 b32 per energies).
// Row stride 48 B: worst aliasing is 2-way (free per m136). Values and FP
// add order IDENTICAL to the legacy path -> bit-exact energies.
__device__ __forceinline__ void fill_sbT(float* sbT, const float* binaries) {
  for (int i = threadIdx.x; i < 288; i += NT) {
    const int n = i / 72, rem = i - n * 72;
    const int ch = rem / 9, nb = rem - ch * 9;
    sbT[n * 108 + nb * 12 + ch] = (nb < 8) ? binaries[n * 64 + ch * 8 + nb]
                                           : 0.0f;
  }
}

__device__ __forceinline__ void energiesT(const float* __restrict__ u,
                                          const float* sbT, int i0, int i1,
                                          int i2, int i3, float* e) {
  const float4* r0 = (const float4*)(sbT +       i0 * 12);
  const float4* r1 = (const float4*)(sbT + 108 + i1 * 12);
  const float4* r2 = (const float4*)(sbT + 216 + i2 * 12);
  const float4* r3 = (const float4*)(sbT + 324 + i3 * 12);
  const float4 a0 = r0[0], b0 = r0[1];
  const float4 a1 = r1[0], b1 = r1[1];
  const float4 a2 = r2[0], b2 = r2[1];
  const float4 a3 = r3[0], b3 = r3[1];
  // Same left-assoc order as reference: ((((u + n0) + n1) + n2) + n3)
  e[0] = u[0] + a0.x + a1.x + a2.x + a3.x;
  e[1] = u[1] + a0.y + a1.y + a2.y + a3.y;
  e[2] = u[2] + a0.z + a1.z + a2.z + a3.z;
  e[3] = u[3] + a0.w + a1.w + a2.w + a3.w;
  e[4] = u[4] + b0.x + b1.x + b2.x + b3.x;
  e[5] = u[5] + b0.y + b1.y + b2.y + b3.y;
  e[6] = u[6] + b0.z + b1.z + b2.z + b3.z;
  e[7] = u[7] + b0.w + b1.w + b2.w + b3.w;
}

// Gumbel-argmax over 8 classes. Partitionable threefry: bits[j] = y0^y1 of
// cipher(key_t, (0, j)), j = flat index into (B,C,H,W); j = ub + ch*HW here.
// Math kept EXACTLY as the proven version (trajectory is bit-sensitive).
__device__ __forceinline__ int gumbel_argmax(const float* e, int ub,
                                             uint32_t k0, uint32_t k1) {
  float zbest = 0.0f;
  int amax = 0;
#pragma unroll
  for (int ch = 0; ch < 8; ++ch) {
    uint32_t y0, y1;
    tf2x32(k0, k1, 0u, (uint32_t)(ub + ch * HW), y0, y1);
    const uint32_t bits = y0 ^ y1;
    const float f = __uint_as_float((bits >> 9) | 0x3F800000u) - 1.0f;
    const float U = (f > 0.0f) ? f : 1.17549435082228751e-38f;
    const float l1 = fast_ln(U);          // ln(U), HW log2 path
    const float gum = -fast_ln(-l1);      // -ln(-ln(U))
    const float z = gum - e[ch];
    if (ch == 0 || z > zbest) { zbest = z; amax = ch; }  // first-max ties
  }
  return amax;
}

// ---------------- prep: repack unaries [B,C,H,W] -> [B,H,W,C] -------------
// One-time ~128 MB of HBM traffic (~25 us). Turns the per-site u[8] load
// from 8x 1-MB-strided dword loads (8 VMEM issues + 8x 64-bit addr calc)
// into 2x dwordx4 at one address. Values identical -> bit-exact.
__global__ __launch_bounds__(NT, 8) void pack_unaries(
    const float* __restrict__ unaries, float* __restrict__ upk) {
  const int tid = blockIdx.x * NT + threadIdx.x;   // flat (b, site)
  const int b = tid >> 18;
  const int site = tid & (HW - 1);
  const int ub = b * CHW + site;
  float4 x, y;
  x.x = unaries[ub];
  x.y = unaries[ub +     HW];
  x.z = unaries[ub + 2 * HW];
  x.w = unaries[ub + 3 * HW];
  y.x = unaries[ub + 4 * HW];
  y.y = unaries[ub + 5 * HW];
  y.z = unaries[ub + 6 * HW];
  y.w = unaries[ub + 7 * HW];
  float4* up = (float4*)(upk + ((size_t)tid << 3));
  up[0] = x; up[1] = y;
}

// ---------------- Pass 1: trajectory only (10 launches) ----------------
// One thread per (b,site). UPACK=1: unaries from packed [B,H,W,C] buffer.
// Neighbor labels (t>0): ONE base address + 4 byte loads at immediate
// offsets +-1 / +-512 into the guard-padded label region; boundary masking
// applied post-load (cndmask) — saves 3 of 4 64-bit address computations.
template <int FIRST, int LAST, int UPACK>
__global__ __launch_bounds__(NT, 8) void traj_step(
    const float* __restrict__ U, const float* __restrict__ binaries,
    const int* __restrict__ s0_int, const uint8_t* __restrict__ s_in,
    uint8_t* __restrict__ s_out, float* __restrict__ sfin,
    uint32_t k0, uint32_t k1) {
  __shared__ __align__(16) float sbT[432];
  fill_sbT(sbT, binaries);
  __syncthreads();

  const int tid = blockIdx.x * NT + threadIdx.x;  // flat (b, r, c)
  const int c = tid & (Wd - 1);
  const int r = (tid >> 9) & (Hd - 1);
  const int b = tid >> 18;
  const int site = tid & (HW - 1);
  const bool v0 = (c + 1) < Wd, v1 = (r + 1) < Hd, v2 = c > 0, v3 = r > 0;

  int i0, i1, i2, i3;
  if (FIRST) {
    // t=0 reads the harness-provided int32 field: predicated addressing
    // (cannot guard-pad an input buffer).
    i0 = v0 ? s0_int[tid + 1]  : 8;
    i1 = v1 ? s0_int[tid + Wd] : 8;
    i2 = v2 ? s0_int[tid - 1]  : 8;
    i3 = v3 ? s0_int[tid - Wd] : 8;
  } else {
    const uint8_t* sp = s_in + tid;       // guard-padded region in ws
    const int n0 = sp[1], n1 = sp[Wd], n2 = sp[-1], n3 = sp[-Wd];
    i0 = v0 ? n0 : 8;
    i1 = v1 ? n1 : 8;
    i2 = v2 ? n2 : 8;
    i3 = v3 ? n3 : 8;
  }

  const int ub = b * CHW + site;   // + ch*HW gives flat (b,ch,r,c)
  float u[8];
  if (UPACK) {
    const float4* up = (const float4*)(U + ((size_t)tid << 3));
    const float4 x = up[0], y = up[1];
    u[0] = x.x; u[1] = x.y; u[2] = x.z; u[3] = x.w;
    u[4] = y.x; u[5] = y.y; u[6] = y.z; u[7] = y.w;
  } else {
#pragma unroll
    for (int ch = 0; ch < 8; ++ch) u[ch] = U[ub + ch * HW];
  }
  float e[8];
  energiesT(u, sbT, i0, i1, i2, i3, e);

  const int amax = gumbel_argmax(e, ub, k0, k1);

  if (LAST) sfin[tid] = (float)amax;          // labels as f32 (output dtype)
  else      s_out[tid] = (uint8_t)amax;
}

// ---------------- Pass 2: marginals only (1 launch) ----------------
template <int UPACK>
__global__ __launch_bounds__(NT, 8) void prob_pass(
    const float* __restrict__ U, const float* __restrict__ binaries,
    const int* __restrict__ s0_int, const uint8_t* __restrict__ sbufs,
    float* __restrict__ acc_out) {
  __shared__ __align__(16) float sbT[432];
  fill_sbT(sbT, binaries);
  __syncthreads();

  const int tid = blockIdx.x * NT + threadIdx.x;
  const int c = tid & (Wd - 1);
  const int r = (tid >> 9) & (Hd - 1);
  const int b = tid >> 18;
  const int site = tid & (HW - 1);
  const bool v0 = (c + 1) < Wd, v1 = (r + 1) < Hd, v2 = c > 0, v3 = r > 0;

  const int ub = b * CHW + site;
  float u[8];
  if (UPACK) {
    const float4* up = (const float4*)(U + ((size_t)tid << 3));
    const float4 x = up[0], y = up[1];
    u[0] = x.x; u[1] = x.y; u[2] = x.z; u[3] = x.w;
    u[4] = y.x; u[5] = y.y; u[6] = y.z; u[7] = y.w;
  } else {
#pragma unroll
    for (int ch = 0; ch < 8; ++ch) u[ch] = U[ub + ch * HW];
  }

  float acc[8] = {};

#pragma unroll 1
  for (int t = 0; t < 10; ++t) {
    int i0, i1, i2, i3;
    if (t == 0) {
      i0 = v0 ? s0_int[tid + 1]  : 8;
      i1 = v1 ? s0_int[tid + Wd] : 8;
      i2 = v2 ? s0_int[tid - 1]  : 8;
      i3 = v3 ? s0_int[tid - Wd] : 8;
    } else {
      const uint8_t* sp = sbufs + (size_t)(t - 1) * BHW + tid;
      const int n0 = sp[1], n1 = sp[Wd], n2 = sp[-1], n3 = sp[-Wd];
      i0 = v0 ? n0 : 8;
      i1 = v1 ? n1 : 8;
      i2 = v2 ? n2 : 8;
      i3 = v3 ? n3 : 8;
    }

    float e[8];
    energiesT(u, sbT, i0, i1, i2, i3, e);

    // softmax(-e). exp2-folded: p = 2^((-e - m)*log2e) via 1 fma + 1 v_exp
    // per class (vs sub+mul+exp). Probs-only rounding change (trajectory
    // does not read these); tolerance headroom 36x.
    float m = -e[0];
#pragma unroll
    for (int ch = 1; ch < 8; ++ch) m = fmaxf(m, -e[ch]);
    const float mm = -m * L2E;
    float p[8];
    float s = 0.0f;
#pragma unroll
    for (int ch = 0; ch < 8; ++ch) {
      p[ch] = __builtin_amdgcn_exp2f(fmaf(e[ch], -L2E, mm));
      s += p[ch];
    }
    const float inv = __builtin_amdgcn_rcpf(s);   // 1-ulp HW reciprocal
#pragma unroll
    for (int ch = 0; ch < 8; ++ch) acc[ch] += p[ch] * inv;
  }

#pragma unroll
  for (int ch = 0; ch < 8; ++ch) acc_out[ub + ch * HW] = acc[ch] * 0.1f;
}

// ---------------- Fallback: round-2 structure (proven, small ws) ----------
__global__ __launch_bounds__(NT) void gibbs_step(
    const float* __restrict__ unaries, const float* __restrict__ binaries,
    const int* __restrict__ s_in, int* __restrict__ s_out,
    float* __restrict__ acc, float* __restrict__ sfin,
    uint32_t k0, uint32_t k1, int mode) {
  __shared__ float sb[288];
  fill_sb(sb, binaries);
  __syncthreads();

  const int tid = blockIdx.x * NT + threadIdx.x;
  const int c = tid & (Wd - 1);
  const int r = (tid >> 9) & (Hd - 1);
  const int b = tid >> 18;
  const int i0 = (c + 1) < Wd ? s_in[tid + 1]  : 8;
  const int i1 = (r + 1) < Hd ? s_in[tid + Wd] : 8;
  const int i2 = c > 0        ? s_in[tid - 1]  : 8;
  const int i3 = r > 0        ? s_in[tid - Wd] : 8;

  const int ub = b * CHW + (tid & (HW - 1));
  float u[8];
#pragma unroll
  for (int ch = 0; ch < 8; ++ch) u[ch] = unaries[ub + ch * HW];
  float e[8];
  energies(u, sb, i0, i1, i2, i3, e);

  const int amax = gumbel_argmax(e, ub, k0, k1);

  float m = -e[0];
#pragma unroll
  for (int ch = 1; ch < 8; ++ch) m = fmaxf(m, -e[ch]);
  float p[8];
  float s = 0.0f;
#pragma unroll
  for (int ch = 0; ch < 8; ++ch) { p[ch] = __expf(-e[ch] - m); s += p[ch]; }
  const float inv = __builtin_amdgcn_rcpf(s);

  if (mode == 0) {
#pragma unroll
    for (int ch = 0; ch < 8; ++ch) acc[ub + ch * HW] = p[ch] * inv;
  } else if (mode == 1) {
#pragma unroll
    for (int ch = 0; ch < 8; ++ch) acc[ub + ch * HW] += p[ch] * inv;
  } else {
#pragma unroll
    for (int ch = 0; ch < 8; ++ch) {
      const int ix = ub + ch * HW;
      acc[ix] = (acc[ix] + p[ch] * inv) * 0.1f;
    }
  }

  if (mode != 2) s_out[tid] = amax;
  else sfin[tid] = (float)amax;
}

// Launch the 10 trajectory steps + prob pass for a given UPACK mode.
template <int UPACK>
static void run_two_pass(const float* U, const float* unaries_orig,
                         const float* binaries, const int* sample0,
                         uint8_t* sbufs, float* acc_out, float* sfin,
                         const uint32_t* ka, const uint32_t* kb,
                         hipStream_t stream) {
  const dim3 grid(BHW / NT), blk(NT);
  for (int t = 0; t < 10; ++t) {
    const uint8_t* sin = (t == 0) ? nullptr : sbufs + (size_t)(t - 1) * BHW;
    uint8_t* sout = (t == 9) ? nullptr : sbufs + (size_t)t * BHW;
    if (t == 0)
      traj_step<1, 0, UPACK><<<grid, blk, 0, stream>>>(
          U, binaries, sample0, nullptr, sout, sfin, ka[t], kb[t]);
    else if (t == 9)
      traj_step<0, 1, UPACK><<<grid, blk, 0, stream>>>(
          U, binaries, nullptr, sin, nullptr, sfin, ka[t], kb[t]);
    else
      traj_step<0, 0, UPACK><<<grid, blk, 0, stream>>>(
          U, binaries, nullptr, sin, sout, sfin, ka[t], kb[t]);
  }
  prob_pass<UPACK><<<grid, blk, 0, stream>>>(U, binaries, sample0, sbufs,
                                             acc_out);
  (void)unaries_orig;
}

extern "C" void kernel_launch(void* const* d_in, const int* in_sizes, int n_in,
                              void* d_out, int out_size, void* d_ws, size_t ws_size,
                              hipStream_t stream) {
  const float* unaries  = (const float*)d_in[0];
  const float* binaries = (const float*)d_in[1];
  const int*   sample0  = (const int*)d_in[2];
  // d_in[3] is sample_steps (=10, fixed by the reference) — hard-coded.

  float* acc_out = (float*)d_out;     // [B,C,H,W] marginals
  float* sfin = acc_out + BCHW;       // s_final (as floats), tail of d_out

  uint32_t ka[10], kb[10];
  for (int t = 0; t < 10; ++t)
    tf2x32(0u, 42u, 0u, (uint32_t)t, ka[t], kb[t]);  // keys[t]=split(key(42))

  // ws layout: [512-B guard][9 uint8 label fields][512-B guard][pad]
  //            [packed unaries, BHW*8 floats]  (packed part optional)
  uint8_t* wsb = (uint8_t*)d_ws;
  const size_t LAB_OFF  = 512;
  const size_t need_lab = LAB_OFF + (size_t)9 * BHW + 512;
  const size_t UPK_OFF  = (need_lab + 255) & ~(size_t)255;
  const size_t need_pak = UPK_OFF + (size_t)BHW * 8 * sizeof(float);
  uint8_t* sbufs = wsb + LAB_OFF;
  float*   upk   = (float*)(wsb + UPK_OFF);

  if (ws_size >= need_pak) {
    pack_unaries<<<dim3(BHW / NT), dim3(NT), 0, stream>>>(unaries, upk);
    run_two_pass<1>(upk, unaries, binaries, sample0, sbufs, acc_out, sfin,
                    ka, kb, stream);
  } else if (ws_size >= need_lab) {
    run_two_pass<0>(unaries, unaries, binaries, sample0, sbufs, acc_out, sfin,
                    ka, kb, stream);
  } else {
    // Fallback (proven in r1/r2): per-step fused kernels, int32 ping-pong.
    int* bufA = (int*)d_ws;
    int* bufB = (int*)sfin;           // pong aliases d_out tail (safe: floats
                                      // only written at t=9, which reads bufA)
    const dim3 grid(BHW / NT), blk(NT);
    for (int t = 0; t < 10; ++t) {
      const int* sin = (t == 0) ? sample0 : ((t & 1) ? bufA : bufB);
      int* sout = (t & 1) ? bufB : bufA;
      const int mode = (t == 0) ? 0 : ((t == 9) ? 2 : 1);
      gibbs_step<<<grid, blk, 0, stream>>>(unaries, binaries, sin, sout,
                                           acc_out, sfin, ka[t], kb[t], mode);
    }
  }
}

// Round 4
// 541.275 us; speedup vs baseline: 5.4253x; 1.0440x over previous
//
#include <hip/hip_runtime.h>
#include <stdint.h>
#include <math.h>

// Problem constants (fixed by the reference: B=8, C=8, H=512, W=512, STEPS=10)
constexpr int Wd = 512;
constexpr int Hd = 512;
constexpr int Cd = 8;
constexpr int Bd = 8;
constexpr int HW = Hd * Wd;        // 262144 = 2^18
constexpr int CHW = Cd * HW;       // 2097152
constexpr int BCHW = Bd * CHW;     // 16777216
constexpr int BHW = Bd * HW;       // 2097152 (= bytes per uint8 label field)
constexpr int NT = 256;

constexpr float LN2 = 0.69314718055994530942f;
constexpr float L2E = 1.44269504088896340736f;   // log2(e)

// Natural log via the HW log2 instruction (v_log_f32, <=1 ulp) + 1 multiply.
__device__ __forceinline__ float fast_ln(float x) {
  return __builtin_amdgcn_logf(x) * LN2;
}

// Threefry-2x32, 20 rounds — bit-exact replica of JAX's threefry2x32 cipher.
// ~72 VALU inst per cipher; 8 ciphers/site/step = 576 inst is the semantic
// floor of this op (measured: ~85% VALUBusy, ~1000 inst/site-step total at
// ~1.6 GHz sustained — the cipher is ~60% of all issue).
__host__ __device__ __forceinline__ void tf2x32(uint32_t k0, uint32_t k1,
                                                uint32_t x0, uint32_t x1,
                                                uint32_t& o0, uint32_t& o1) {
  const uint32_t k2 = k0 ^ k1 ^ 0x1BD11BDAu;
  x0 += k0; x1 += k1;
#define TFR(r) { x0 += x1; x1 = __builtin_rotateleft32(x1, (r)); x1 ^= x0; }
  TFR(13) TFR(15) TFR(26) TFR(6)
  x0 += k1; x1 += k2 + 1u;
  TFR(17) TFR(29) TFR(16) TFR(24)
  x0 += k2; x1 += k0 + 2u;
  TFR(13) TFR(15) TFR(26) TFR(6)
  x0 += k0; x1 += k1 + 3u;
  TFR(17) TFR(29) TFR(16) TFR(24)
  x0 += k1; x1 += k2 + 4u;
  TFR(13) TFR(15) TFR(26) TFR(6)
  x0 += k2; x1 += k0 + 5u;
#undef TFR
  o0 = x0; o1 = x1;
}

// ---------- legacy zero-slot table (kept for the gibbs_step fallback) ------
__device__ __forceinline__ void fill_sb(float* sb, const float* binaries) {
  for (int i = threadIdx.x; i < 288; i += NT) {
    const int n = i / 72, rem = i - n * 72;
    const int ch = rem / 9, nb = rem - ch * 9;
    sb[i] = (nb < 8) ? binaries[n * 64 + ch * 8 + nb] : 0.0f;
  }
}

__device__ __forceinline__ void energies(const float* __restrict__ u,
                                         const float* sb, int i0, int i1,
                                         int i2, int i3, float* e) {
#pragma unroll
  for (int ch = 0; ch < 8; ++ch) {
    float v = u[ch];
    v += sb[      ch * 9 + i0];
    v += sb[ 72 + ch * 9 + i1];
    v += sb[144 + ch * 9 + i2];
    v += sb[216 + ch * 9 + i3];
    e[ch] = v;
  }
}

// ---------- transposed table: sbT[n][nb][ch], row padded to 12 floats -----
// Reads are 2x ds_read_b128 per neighbor (8 b128 vs 32 b32 per energies).
// Row stride 48 B: worst aliasing is 2-way (free per m136). Values and FP
// add order IDENTICAL to the legacy path -> bit-exact energies.
__device__ __forceinline__ void fill_sbT(float* sbT, const float* binaries) {
  for (int i = threadIdx.x; i < 288; i += NT) {
    const int n = i / 72, rem = i - n * 72;
    const int ch = rem / 9, nb = rem - ch * 9;
    sbT[n * 108 + nb * 12 + ch] = (nb < 8) ? binaries[n * 64 + ch * 8 + nb]
                                           : 0.0f;
  }
}

__device__ __forceinline__ void energiesT(const float* __restrict__ u,
                                          const float* sbT, int i0, int i1,
                                          int i2, int i3, float* e) {
  const float4* r0 = (const float4*)(sbT +       i0 * 12);
  const float4* r1 = (const float4*)(sbT + 108 + i1 * 12);
  const float4* r2 = (const float4*)(sbT + 216 + i2 * 12);
  const float4* r3 = (const float4*)(sbT + 324 + i3 * 12);
  const float4 a0 = r0[0], b0 = r0[1];
  const float4 a1 = r1[0], b1 = r1[1];
  const float4 a2 = r2[0], b2 = r2[1];
  const float4 a3 = r3[0], b3 = r3[1];
  // Same left-assoc order as reference: ((((u + n0) + n1) + n2) + n3)
  e[0] = u[0] + a0.x + a1.x + a2.x + a3.x;
  e[1] = u[1] + a0.y + a1.y + a2.y + a3.y;
  e[2] = u[2] + a0.z + a1.z + a2.z + a3.z;
  e[3] = u[3] + a0.w + a1.w + a2.w + a3.w;
  e[4] = u[4] + b0.x + b1.x + b2.x + b3.x;
  e[5] = u[5] + b0.y + b1.y + b2.y + b3.y;
  e[6] = u[6] + b0.z + b1.z + b2.z + b3.z;
  e[7] = u[7] + b0.w + b1.w + b2.w + b3.w;
}

// Gumbel-argmax over 8 classes. Partitionable threefry: bits[j] = y0^y1 of
// cipher(key_t, (0, j)), j = flat index into (B,C,H,W); j = ub + ch*HW here.
// Math kept EXACTLY as the proven version (trajectory is bit-sensitive).
__device__ __forceinline__ int gumbel_argmax(const float* e, int ub,
                                             uint32_t k0, uint32_t k1) {
  float zbest = 0.0f;
  int amax = 0;
#pragma unroll
  for (int ch = 0; ch < 8; ++ch) {
    uint32_t y0, y1;
    tf2x32(k0, k1, 0u, (uint32_t)(ub + ch * HW), y0, y1);
    const uint32_t bits = y0 ^ y1;
    const float f = __uint_as_float((bits >> 9) | 0x3F800000u) - 1.0f;
    const float U = (f > 0.0f) ? f : 1.17549435082228751e-38f;
    const float l1 = fast_ln(U);          // ln(U), HW log2 path
    const float gum = -fast_ln(-l1);      // -ln(-ln(U))
    const float z = gum - e[ch];
    if (ch == 0 || z > zbest) { zbest = z; amax = ch; }  // first-max ties
  }
  return amax;
}

// ---------------- Pass 1: trajectory only (10 launches) ----------------
// One thread per (b,site). UPACK=1: steps 1..9 read unaries from the packed
// [B,H,W,C] buffer (2x dwordx4, one address). Step 0 reads the original
// strided layout and WRITES the packed buffer as a side effect (2 dwordx4
// stores, hidden under the 85%-busy VALU) — no separate packing pass.
// Neighbor labels (t>0): ONE base address + 4 byte loads at immediate
// offsets +-1 / +-512 into the guard-padded label region; boundary masking
// applied post-load (cndmask).
template <int FIRST, int LAST, int UPACK>
__global__ __launch_bounds__(NT, 8) void traj_step(
    const float* __restrict__ Uorig, float* __restrict__ upk,
    const float* __restrict__ binaries,
    const int* __restrict__ s0_int, const uint8_t* __restrict__ s_in,
    uint8_t* __restrict__ s_out, float* __restrict__ sfin,
    uint32_t k0, uint32_t k1) {
  __shared__ __align__(16) float sbT[432];
  fill_sbT(sbT, binaries);
  __syncthreads();

  const int tid = blockIdx.x * NT + threadIdx.x;  // flat (b, r, c)
  const int c = tid & (Wd - 1);
  const int r = (tid >> 9) & (Hd - 1);
  const int b = tid >> 18;
  const int site = tid & (HW - 1);
  const bool v0 = (c + 1) < Wd, v1 = (r + 1) < Hd, v2 = c > 0, v3 = r > 0;

  int i0, i1, i2, i3;
  if (FIRST) {
    // t=0 reads the harness-provided int32 field: predicated addressing
    // (cannot guard-pad an input buffer).
    i0 = v0 ? s0_int[tid + 1]  : 8;
    i1 = v1 ? s0_int[tid + Wd] : 8;
    i2 = v2 ? s0_int[tid - 1]  : 8;
    i3 = v3 ? s0_int[tid - Wd] : 8;
  } else {
    const uint8_t* sp = s_in + tid;       // guard-padded region in ws
    const int n0 = sp[1], n1 = sp[Wd], n2 = sp[-1], n3 = sp[-Wd];
    i0 = v0 ? n0 : 8;
    i1 = v1 ? n1 : 8;
    i2 = v2 ? n2 : 8;
    i3 = v3 ? n3 : 8;
  }

  const int ub = b * CHW + site;   // + ch*HW gives flat (b,ch,r,c)
  float u[8];
  if (UPACK && !FIRST) {
    const float4* up = (const float4*)(upk + ((size_t)tid << 3));
    const float4 x = up[0], y = up[1];
    u[0] = x.x; u[1] = x.y; u[2] = x.z; u[3] = x.w;
    u[4] = y.x; u[5] = y.y; u[6] = y.z; u[7] = y.w;
  } else {
#pragma unroll
    for (int ch = 0; ch < 8; ++ch) u[ch] = Uorig[ub + ch * HW];
    if (UPACK && FIRST) {
      // write-through pack: pure copy, bit-exact, replaces pack_unaries
      float4 x, y;
      x.x = u[0]; x.y = u[1]; x.z = u[2]; x.w = u[3];
      y.x = u[4]; y.y = u[5]; y.z = u[6]; y.w = u[7];
      float4* up = (float4*)(upk + ((size_t)tid << 3));
      up[0] = x; up[1] = y;
    }
  }
  float e[8];
  energiesT(u, sbT, i0, i1, i2, i3, e);

  const int amax = gumbel_argmax(e, ub, k0, k1);

  if (LAST) sfin[tid] = (float)amax;          // labels as f32 (output dtype)
  else      s_out[tid] = (uint8_t)amax;
}

// ---------------- Pass 2: marginals only (1 launch) ----------------
template <int UPACK>
__global__ __launch_bounds__(NT, 8) void prob_pass(
    const float* __restrict__ U, const float* __restrict__ binaries,
    const int* __restrict__ s0_int, const uint8_t* __restrict__ sbufs,
    float* __restrict__ acc_out) {
  __shared__ __align__(16) float sbT[432];
  fill_sbT(sbT, binaries);
  __syncthreads();

  const int tid = blockIdx.x * NT + threadIdx.x;
  const int c = tid & (Wd - 1);
  const int r = (tid >> 9) & (Hd - 1);
  const int b = tid >> 18;
  const int site = tid & (HW - 1);
  const bool v0 = (c + 1) < Wd, v1 = (r + 1) < Hd, v2 = c > 0, v3 = r > 0;

  const int ub = b * CHW + site;
  float u[8];
  if (UPACK) {
    const float4* up = (const float4*)(U + ((size_t)tid << 3));
    const float4 x = up[0], y = up[1];
    u[0] = x.x; u[1] = x.y; u[2] = x.z; u[3] = x.w;
    u[4] = y.x; u[5] = y.y; u[6] = y.z; u[7] = y.w;
  } else {
#pragma unroll
    for (int ch = 0; ch < 8; ++ch) u[ch] = U[ub + ch * HW];
  }

  float acc[8] = {};

#pragma unroll 1
  for (int t = 0; t < 10; ++t) {
    int i0, i1, i2, i3;
    if (t == 0) {
      i0 = v0 ? s0_int[tid + 1]  : 8;
      i1 = v1 ? s0_int[tid + Wd] : 8;
      i2 = v2 ? s0_int[tid - 1]  : 8;
      i3 = v3 ? s0_int[tid - Wd] : 8;
    } else {
      const uint8_t* sp = sbufs + (size_t)(t - 1) * BHW + tid;
      const int n0 = sp[1], n1 = sp[Wd], n2 = sp[-1], n3 = sp[-Wd];
      i0 = v0 ? n0 : 8;
      i1 = v1 ? n1 : 8;
      i2 = v2 ? n2 : 8;
      i3 = v3 ? n3 : 8;
    }

    float e[8];
    energiesT(u, sbT, i0, i1, i2, i3, e);

    // softmax(-e). exp2-folded: p = 2^((-e - m)*log2e) via 1 fma + 1 v_exp
    // per class. Probs-only rounding change (trajectory does not read
    // these); tolerance headroom 36x.
    float m = -e[0];
#pragma unroll
    for (int ch = 1; ch < 8; ++ch) m = fmaxf(m, -e[ch]);
    const float mm = -m * L2E;
    float p[8];
    float s = 0.0f;
#pragma unroll
    for (int ch = 0; ch < 8; ++ch) {
      p[ch] = __builtin_amdgcn_exp2f(fmaf(e[ch], -L2E, mm));
      s += p[ch];
    }
    const float inv = __builtin_amdgcn_rcpf(s);   // 1-ulp HW reciprocal
#pragma unroll
    for (int ch = 0; ch < 8; ++ch) acc[ch] += p[ch] * inv;
  }

#pragma unroll
  for (int ch = 0; ch < 8; ++ch) acc_out[ub + ch * HW] = acc[ch] * 0.1f;
}

// ---------------- Fallback: round-2 structure (proven, small ws) ----------
__global__ __launch_bounds__(NT) void gibbs_step(
    const float* __restrict__ unaries, const float* __restrict__ binaries,
    const int* __restrict__ s_in, int* __restrict__ s_out,
    float* __restrict__ acc, float* __restrict__ sfin,
    uint32_t k0, uint32_t k1, int mode) {
  __shared__ float sb[288];
  fill_sb(sb, binaries);
  __syncthreads();

  const int tid = blockIdx.x * NT + threadIdx.x;
  const int c = tid & (Wd - 1);
  const int r = (tid >> 9) & (Hd - 1);
  const int b = tid >> 18;
  const int i0 = (c + 1) < Wd ? s_in[tid + 1]  : 8;
  const int i1 = (r + 1) < Hd ? s_in[tid + Wd] : 8;
  const int i2 = c > 0        ? s_in[tid - 1]  : 8;
  const int i3 = r > 0        ? s_in[tid - Wd] : 8;

  const int ub = b * CHW + (tid & (HW - 1));
  float u[8];
#pragma unroll
  for (int ch = 0; ch < 8; ++ch) u[ch] = unaries[ub + ch * HW];
  float e[8];
  energies(u, sb, i0, i1, i2, i3, e);

  const int amax = gumbel_argmax(e, ub, k0, k1);

  float m = -e[0];
#pragma unroll
  for (int ch = 1; ch < 8; ++ch) m = fmaxf(m, -e[ch]);
  float p[8];
  float s = 0.0f;
#pragma unroll
  for (int ch = 0; ch < 8; ++ch) { p[ch] = __expf(-e[ch] - m); s += p[ch]; }
  const float inv = __builtin_amdgcn_rcpf(s);

  if (mode == 0) {
#pragma unroll
    for (int ch = 0; ch < 8; ++ch) acc[ub + ch * HW] = p[ch] * inv;
  } else if (mode == 1) {
#pragma unroll
    for (int ch = 0; ch < 8; ++ch) acc[ub + ch * HW] += p[ch] * inv;
  } else {
#pragma unroll
    for (int ch = 0; ch < 8; ++ch) {
      const int ix = ub + ch * HW;
      acc[ix] = (acc[ix] + p[ch] * inv) * 0.1f;
    }
  }

  if (mode != 2) s_out[tid] = amax;
  else sfin[tid] = (float)amax;
}

// Launch the 10 trajectory steps + prob pass for a given UPACK mode.
template <int UPACK>
static void run_two_pass(const float* unaries, float* upk,
                         const float* binaries, const int* sample0,
                         uint8_t* sbufs, float* acc_out, float* sfin,
                         const uint32_t* ka, const uint32_t* kb,
                         hipStream_t stream) {
  const dim3 grid(BHW / NT), blk(NT);
  for (int t = 0; t < 10; ++t) {
    const uint8_t* sin = (t == 0) ? nullptr : sbufs + (size_t)(t - 1) * BHW;
    uint8_t* sout = (t == 9) ? nullptr : sbufs + (size_t)t * BHW;
    if (t == 0)
      traj_step<1, 0, UPACK><<<grid, blk, 0, stream>>>(
          unaries, upk, binaries, sample0, nullptr, sout, sfin, ka[t], kb[t]);
    else if (t == 9)
      traj_step<0, 1, UPACK><<<grid, blk, 0, stream>>>(
          unaries, upk, binaries, nullptr, sin, nullptr, sfin, ka[t], kb[t]);
    else
      traj_step<0, 0, UPACK><<<grid, blk, 0, stream>>>(
          unaries, upk, binaries, nullptr, sin, sout, sfin, ka[t], kb[t]);
  }
  const float* U = UPACK ? (const float*)upk : unaries;
  prob_pass<UPACK><<<grid, blk, 0, stream>>>(U, binaries, sample0, sbufs,
                                             acc_out);
}

extern "C" void kernel_launch(void* const* d_in, const int* in_sizes, int n_in,
                              void* d_out, int out_size, void* d_ws, size_t ws_size,
                              hipStream_t stream) {
  const float* unaries  = (const float*)d_in[0];
  const float* binaries = (const float*)d_in[1];
  const int*   sample0  = (const int*)d_in[2];
  // d_in[3] is sample_steps (=10, fixed by the reference) — hard-coded.

  float* acc_out = (float*)d_out;     // [B,C,H,W] marginals
  float* sfin = acc_out + BCHW;       // s_final (as floats), tail of d_out

  uint32_t ka[10], kb[10];
  for (int t = 0; t < 10; ++t)
    tf2x32(0u, 42u, 0u, (uint32_t)t, ka[t], kb[t]);  // keys[t]=split(key(42))

  // ws layout: [512-B guard][9 uint8 label fields][512-B guard][pad]
  //            [packed unaries, BHW*8 floats]  (packed part optional)
  uint8_t* wsb = (uint8_t*)d_ws;
  const size_t LAB_OFF  = 512;
  const size_t need_lab = LAB_OFF + (size_t)9 * BHW + 512;
  const size_t UPK_OFF  = (need_lab + 255) & ~(size_t)255;
  const size_t need_pak = UPK_OFF + (size_t)BHW * 8 * sizeof(float);
  uint8_t* sbufs = wsb + LAB_OFF;
  float*   upk   = (float*)(wsb + UPK_OFF);

  if (ws_size >= need_pak) {
    run_two_pass<1>(unaries, upk, binaries, sample0, sbufs, acc_out, sfin,
                    ka, kb, stream);
  } else if (ws_size >= need_lab) {
    run_two_pass<0>(unaries, nullptr, binaries, sample0, sbufs, acc_out, sfin,
                    ka, kb, stream);
  } else {
    // Fallback (proven in r1/r2): per-step fused kernels, int32 ping-pong.
    int* bufA = (int*)d_ws;
    int* bufB = (int*)sfin;           // pong aliases d_out tail (safe: floats
                                      // only written at t=9, which reads bufA)
    const dim3 grid(BHW / NT), blk(NT);
    for (int t = 0; t < 10; ++t) {
      const int* sin = (t == 0) ? sample0 : ((t & 1) ? bufA : bufB);
      int* sout = (t & 1) ? bufB : bufA;
      const int mode = (t == 0) ? 0 : ((t == 9) ? 2 : 1);
      gibbs_step<<<grid, blk, 0, stream>>>(unaries, binaries, sin, sout,
                                           acc_out, sfin, ka[t], kb[t], mode);
    }
  }
}

// Round 5
// 530.186 us; speedup vs baseline: 5.5388x; 1.0209x over previous
//
#include <hip/hip_runtime.h>
#include <stdint.h>
#include <math.h>

// Problem constants (fixed by the reference: B=8, C=8, H=512, W=512, STEPS=10)
constexpr int Wd = 512;
constexpr int Hd = 512;
constexpr int Cd = 8;
constexpr int Bd = 8;
constexpr int HW = Hd * Wd;        // 262144 = 2^18
constexpr int CHW = Cd * HW;       // 2097152
constexpr int BCHW = Bd * CHW;     // 16777216
constexpr int BHW = Bd * HW;       // 2097152 (= bytes per uint8 label field)
constexpr int NT = 256;

constexpr float LN2 = 0.69314718055994530942f;
constexpr float L2E = 1.44269504088896340736f;   // log2(e)

// Natural log via the HW log2 instruction (v_log_f32, <=1 ulp) + 1 multiply.
__device__ __forceinline__ float fast_ln(float x) {
  return __builtin_amdgcn_logf(x) * LN2;
}

// Threefry-2x32, 20 rounds — bit-exact replica of JAX's threefry2x32 cipher.
// ~72 VALU inst per cipher; 8 ciphers/site/step = 576 inst is the semantic
// floor of this op. Measured: mid traj steps run at their static inst count
// (~1000 slot-equivalents/site-step) at 85% VALUBusy — issue-bound floor.
__host__ __device__ __forceinline__ void tf2x32(uint32_t k0, uint32_t k1,
                                                uint32_t x0, uint32_t x1,
                                                uint32_t& o0, uint32_t& o1) {
  const uint32_t k2 = k0 ^ k1 ^ 0x1BD11BDAu;
  x0 += k0; x1 += k1;
#define TFR(r) { x0 += x1; x1 = __builtin_rotateleft32(x1, (r)); x1 ^= x0; }
  TFR(13) TFR(15) TFR(26) TFR(6)
  x0 += k1; x1 += k2 + 1u;
  TFR(17) TFR(29) TFR(16) TFR(24)
  x0 += k2; x1 += k0 + 2u;
  TFR(13) TFR(15) TFR(26) TFR(6)
  x0 += k0; x1 += k1 + 3u;
  TFR(17) TFR(29) TFR(16) TFR(24)
  x0 += k1; x1 += k2 + 4u;
  TFR(13) TFR(15) TFR(26) TFR(6)
  x0 += k2; x1 += k0 + 5u;
#undef TFR
  o0 = x0; o1 = x1;
}

// ---------- legacy zero-slot table (kept for the gibbs_step fallback) ------
__device__ __forceinline__ void fill_sb(float* sb, const float* binaries) {
  for (int i = threadIdx.x; i < 288; i += NT) {
    const int n = i / 72, rem = i - n * 72;
    const int ch = rem / 9, nb = rem - ch * 9;
    sb[i] = (nb < 8) ? binaries[n * 64 + ch * 8 + nb] : 0.0f;
  }
}

__device__ __forceinline__ void energies(const float* __restrict__ u,
                                         const float* sb, int i0, int i1,
                                         int i2, int i3, float* e) {
#pragma unroll
  for (int ch = 0; ch < 8; ++ch) {
    float v = u[ch];
    v += sb[      ch * 9 + i0];
    v += sb[ 72 + ch * 9 + i1];
    v += sb[144 + ch * 9 + i2];
    v += sb[216 + ch * 9 + i3];
    e[ch] = v;
  }
}

// ---------- transposed table: sbT[n][nb][ch], row padded to 12 floats -----
// Reads are 2x ds_read_b128 per neighbor (8 b128 vs 32 b32 per energies).
// Row stride 48 B: worst aliasing is 2-way (free per m136). Values and FP
// add order IDENTICAL to the legacy path -> bit-exact energies.
__device__ __forceinline__ void fill_sbT(float* sbT, const float* binaries) {
  for (int i = threadIdx.x; i < 288; i += NT) {
    const int n = i / 72, rem = i - n * 72;
    const int ch = rem / 9, nb = rem - ch * 9;
    sbT[n * 108 + nb * 12 + ch] = (nb < 8) ? binaries[n * 64 + ch * 8 + nb]
                                           : 0.0f;
  }
}

__device__ __forceinline__ void energiesT(const float* __restrict__ u,
                                          const float* sbT, int i0, int i1,
                                          int i2, int i3, float* e) {
  const float4* r0 = (const float4*)(sbT +       i0 * 12);
  const float4* r1 = (const float4*)(sbT + 108 + i1 * 12);
  const float4* r2 = (const float4*)(sbT + 216 + i2 * 12);
  const float4* r3 = (const float4*)(sbT + 324 + i3 * 12);
  const float4 a0 = r0[0], b0 = r0[1];
  const float4 a1 = r1[0], b1 = r1[1];
  const float4 a2 = r2[0], b2 = r2[1];
  const float4 a3 = r3[0], b3 = r3[1];
  // Same left-assoc order as reference: ((((u + n0) + n1) + n2) + n3)
  e[0] = u[0] + a0.x + a1.x + a2.x + a3.x;
  e[1] = u[1] + a0.y + a1.y + a2.y + a3.y;
  e[2] = u[2] + a0.z + a1.z + a2.z + a3.z;
  e[3] = u[3] + a0.w + a1.w + a2.w + a3.w;
  e[4] = u[4] + b0.x + b1.x + b2.x + b3.x;
  e[5] = u[5] + b0.y + b1.y + b2.y + b3.y;
  e[6] = u[6] + b0.z + b1.z + b2.z + b3.z;
  e[7] = u[7] + b0.w + b1.w + b2.w + b3.w;
}

// Gumbel-argmax over 8 classes. Partitionable threefry: bits[j] = y0^y1 of
// cipher(key_t, (0, j)), j = flat index into (B,C,H,W); j = ub + ch*HW here.
// Math kept EXACTLY as the proven version (trajectory is bit-sensitive:
// one argmax flip = integer-sized error in s_final).
__device__ __forceinline__ int gumbel_argmax(const float* e, int ub,
                                             uint32_t k0, uint32_t k1) {
  float zbest = 0.0f;
  int amax = 0;
#pragma unroll
  for (int ch = 0; ch < 8; ++ch) {
    uint32_t y0, y1;
    tf2x32(k0, k1, 0u, (uint32_t)(ub + ch * HW), y0, y1);
    const uint32_t bits = y0 ^ y1;
    const float f = __uint_as_float((bits >> 9) | 0x3F800000u) - 1.0f;
    const float U = (f > 0.0f) ? f : 1.17549435082228751e-38f;
    const float l1 = fast_ln(U);          // ln(U), HW log2 path
    const float gum = -fast_ln(-l1);      // -ln(-ln(U))
    const float z = gum - e[ch];
    if (ch == 0 || z > zbest) { zbest = z; amax = ch; }  // first-max ties
  }
  return amax;
}

// ---------------- Pass 1: trajectory, steps 0..8 (9 launches) -------------
// One thread per (b,site). UPACK=1: steps 1..8 read unaries from the packed
// [B,H,W,C] buffer (2x dwordx4, one address). Step 0 reads the original
// strided layout and WRITES the packed buffer as a side effect (2 dwordx4
// stores) — no separate packing pass.
// Step 9 no longer exists as a trajectory launch: its energies are bit-
// identical to the replay kernel's t=9 iteration, so the final gumbel draw
// is fused into prob_final (saves a full dispatch of shared work).
template <int FIRST, int UPACK>
__global__ __launch_bounds__(NT, 8) void traj_step(
    const float* __restrict__ Uorig, float* __restrict__ upk,
    const float* __restrict__ binaries,
    const int* __restrict__ s0_int, const uint8_t* __restrict__ s_in,
    uint8_t* __restrict__ s_out,
    uint32_t k0, uint32_t k1) {
  __shared__ __align__(16) float sbT[432];
  fill_sbT(sbT, binaries);
  __syncthreads();

  const int tid = blockIdx.x * NT + threadIdx.x;  // flat (b, r, c)
  const int c = tid & (Wd - 1);
  const int r = (tid >> 9) & (Hd - 1);
  const int b = tid >> 18;
  const int site = tid & (HW - 1);
  const bool v0 = (c + 1) < Wd, v1 = (r + 1) < Hd, v2 = c > 0, v3 = r > 0;

  int i0, i1, i2, i3;
  if (FIRST) {
    // t=0 reads the harness-provided int32 field: predicated addressing
    // (cannot guard-pad an input buffer).
    i0 = v0 ? s0_int[tid + 1]  : 8;
    i1 = v1 ? s0_int[tid + Wd] : 8;
    i2 = v2 ? s0_int[tid - 1]  : 8;
    i3 = v3 ? s0_int[tid - Wd] : 8;
  } else {
    const uint8_t* sp = s_in + tid;       // guard-padded region in ws
    const int n0 = sp[1], n1 = sp[Wd], n2 = sp[-1], n3 = sp[-Wd];
    i0 = v0 ? n0 : 8;
    i1 = v1 ? n1 : 8;
    i2 = v2 ? n2 : 8;
    i3 = v3 ? n3 : 8;
  }

  const int ub = b * CHW + site;   // + ch*HW gives flat (b,ch,r,c)
  float u[8];
  if (UPACK && !FIRST) {
    const float4* up = (const float4*)(upk + ((size_t)tid << 3));
    const float4 x = up[0], y = up[1];
    u[0] = x.x; u[1] = x.y; u[2] = x.z; u[3] = x.w;
    u[4] = y.x; u[5] = y.y; u[6] = y.z; u[7] = y.w;
  } else {
#pragma unroll
    for (int ch = 0; ch < 8; ++ch) u[ch] = Uorig[ub + ch * HW];
    if (UPACK && FIRST) {
      // write-through pack: pure copy, bit-exact, replaces pack_unaries
      float4 x, y;
      x.x = u[0]; x.y = u[1]; x.z = u[2]; x.w = u[3];
      y.x = u[4]; y.y = u[5]; y.z = u[6]; y.w = u[7];
      float4* up = (float4*)(upk + ((size_t)tid << 3));
      up[0] = x; up[1] = y;
    }
  }
  float e[8];
  energiesT(u, sbT, i0, i1, i2, i3, e);

  const int amax = gumbel_argmax(e, ub, k0, k1);

  s_out[tid] = (uint8_t)amax;
}

// ---------- Pass 2: marginals replay + fused final gumbel draw ------------
// Replays steps 0..9 from stored labels, accumulating softmax in registers.
// The t=9 iteration's e[8] is bit-identical to what a standalone step-9
// trajectory kernel would compute (same labels sbufs[8], same energiesT,
// same add order) — so the final gumbel-argmax is drawn here and written
// to sfin, deleting the standalone t=9 dispatch entirely.
template <int UPACK>
__global__ __launch_bounds__(NT, 8) void prob_final(
    const float* __restrict__ U, const float* __restrict__ binaries,
    const int* __restrict__ s0_int, const uint8_t* __restrict__ sbufs,
    float* __restrict__ acc_out, float* __restrict__ sfin,
    uint32_t k9a, uint32_t k9b) {
  __shared__ __align__(16) float sbT[432];
  fill_sbT(sbT, binaries);
  __syncthreads();

  const int tid = blockIdx.x * NT + threadIdx.x;
  const int c = tid & (Wd - 1);
  const int r = (tid >> 9) & (Hd - 1);
  const int b = tid >> 18;
  const int site = tid & (HW - 1);
  const bool v0 = (c + 1) < Wd, v1 = (r + 1) < Hd, v2 = c > 0, v3 = r > 0;

  const int ub = b * CHW + site;
  float u[8];
  if (UPACK) {
    const float4* up = (const float4*)(U + ((size_t)tid << 3));
    const float4 x = up[0], y = up[1];
    u[0] = x.x; u[1] = x.y; u[2] = x.z; u[3] = x.w;
    u[4] = y.x; u[5] = y.y; u[6] = y.z; u[7] = y.w;
  } else {
#pragma unroll
    for (int ch = 0; ch < 8; ++ch) u[ch] = U[ub + ch * HW];
  }

  float acc[8] = {};

#pragma unroll 1
  for (int t = 0; t < 10; ++t) {
    int i0, i1, i2, i3;
    if (t == 0) {
      i0 = v0 ? s0_int[tid + 1]  : 8;
      i1 = v1 ? s0_int[tid + Wd] : 8;
      i2 = v2 ? s0_int[tid - 1]  : 8;
      i3 = v3 ? s0_int[tid - Wd] : 8;
    } else {
      const uint8_t* sp = sbufs + (size_t)(t - 1) * BHW + tid;
      const int n0 = sp[1], n1 = sp[Wd], n2 = sp[-1], n3 = sp[-Wd];
      i0 = v0 ? n0 : 8;
      i1 = v1 ? n1 : 8;
      i2 = v2 ? n2 : 8;
      i3 = v3 ? n3 : 8;
    }

    float e[8];
    energiesT(u, sbT, i0, i1, i2, i3, e);

    // softmax(-e). exp2-folded: p = 2^((-e - m)*log2e) via 1 fma + 1 v_exp
    // per class. Probs-only rounding change (trajectory does not read
    // these); tolerance headroom 36x.
    float m = -e[0];
#pragma unroll
    for (int ch = 1; ch < 8; ++ch) m = fmaxf(m, -e[ch]);
    const float mm = -m * L2E;
    float p[8];
    float s = 0.0f;
#pragma unroll
    for (int ch = 0; ch < 8; ++ch) {
      p[ch] = __builtin_amdgcn_exp2f(fmaf(e[ch], -L2E, mm));
      s += p[ch];
    }
    const float inv = __builtin_amdgcn_rcpf(s);   // 1-ulp HW reciprocal
#pragma unroll
    for (int ch = 0; ch < 8; ++ch) acc[ch] += p[ch] * inv;

    if (t == 9) {
      // fused step-9 draw: e is bit-identical to a standalone traj t=9
      const int amax = gumbel_argmax(e, ub, k9a, k9b);
      sfin[tid] = (float)amax;
    }
  }

#pragma unroll
  for (int ch = 0; ch < 8; ++ch) acc_out[ub + ch * HW] = acc[ch] * 0.1f;
}

// ---------------- Fallback: round-2 structure (proven, small ws) ----------
__global__ __launch_bounds__(NT) void gibbs_step(
    const float* __restrict__ unaries, const float* __restrict__ binaries,
    const int* __restrict__ s_in, int* __restrict__ s_out,
    float* __restrict__ acc, float* __restrict__ sfin,
    uint32_t k0, uint32_t k1, int mode) {
  __shared__ float sb[288];
  fill_sb(sb, binaries);
  __syncthreads();

  const int tid = blockIdx.x * NT + threadIdx.x;
  const int c = tid & (Wd - 1);
  const int r = (tid >> 9) & (Hd - 1);
  const int b = tid >> 18;
  const int i0 = (c + 1) < Wd ? s_in[tid + 1]  : 8;
  const int i1 = (r + 1) < Hd ? s_in[tid + Wd] : 8;
  const int i2 = c > 0        ? s_in[tid - 1]  : 8;
  const int i3 = r > 0        ? s_in[tid - Wd] : 8;

  const int ub = b * CHW + (tid & (HW - 1));
  float u[8];
#pragma unroll
  for (int ch = 0; ch < 8; ++ch) u[ch] = unaries[ub + ch * HW];
  float e[8];
  energies(u, sb, i0, i1, i2, i3, e);

  const int amax = gumbel_argmax(e, ub, k0, k1);

  float m = -e[0];
#pragma unroll
  for (int ch = 1; ch < 8; ++ch) m = fmaxf(m, -e[ch]);
  float p[8];
  float s = 0.0f;
#pragma unroll
  for (int ch = 0; ch < 8; ++ch) { p[ch] = __expf(-e[ch] - m); s += p[ch]; }
  const float inv = __builtin_amdgcn_rcpf(s);

  if (mode == 0) {
#pragma unroll
    for (int ch = 0; ch < 8; ++ch) acc[ub + ch * HW] = p[ch] * inv;
  } else if (mode == 1) {
#pragma unroll
    for (int ch = 0; ch < 8; ++ch) acc[ub + ch * HW] += p[ch] * inv;
  } else {
#pragma unroll
    for (int ch = 0; ch < 8; ++ch) {
      const int ix = ub + ch * HW;
      acc[ix] = (acc[ix] + p[ch] * inv) * 0.1f;
    }
  }

  if (mode != 2) s_out[tid] = amax;
  else sfin[tid] = (float)amax;
}

// Launch the 9 trajectory steps + merged replay/final for a given UPACK mode.
template <int UPACK>
static void run_two_pass(const float* unaries, float* upk,
                         const float* binaries, const int* sample0,
                         uint8_t* sbufs, float* acc_out, float* sfin,
                         const uint32_t* ka, const uint32_t* kb,
                         hipStream_t stream) {
  const dim3 grid(BHW / NT), blk(NT);
  for (int t = 0; t < 9; ++t) {
    const uint8_t* sin = (t == 0) ? nullptr : sbufs + (size_t)(t - 1) * BHW;
    uint8_t* sout = sbufs + (size_t)t * BHW;
    if (t == 0)
      traj_step<1, UPACK><<<grid, blk, 0, stream>>>(
          unaries, upk, binaries, sample0, nullptr, sout, ka[t], kb[t]);
    else
      traj_step<0, UPACK><<<grid, blk, 0, stream>>>(
          unaries, upk, binaries, nullptr, sin, sout, ka[t], kb[t]);
  }
  const float* U = UPACK ? (const float*)upk : unaries;
  prob_final<UPACK><<<grid, blk, 0, stream>>>(U, binaries, sample0, sbufs,
                                              acc_out, sfin, ka[9], kb[9]);
}

extern "C" void kernel_launch(void* const* d_in, const int* in_sizes, int n_in,
                              void* d_out, int out_size, void* d_ws, size_t ws_size,
                              hipStream_t stream) {
  const float* unaries  = (const float*)d_in[0];
  const float* binaries = (const float*)d_in[1];
  const int*   sample0  = (const int*)d_in[2];
  // d_in[3] is sample_steps (=10, fixed by the reference) — hard-coded.

  float* acc_out = (float*)d_out;     // [B,C,H,W] marginals
  float* sfin = acc_out + BCHW;       // s_final (as floats), tail of d_out

  uint32_t ka[10], kb[10];
  for (int t = 0; t < 10; ++t)
    tf2x32(0u, 42u, 0u, (uint32_t)t, ka[t], kb[t]);  // keys[t]=split(key(42))

  // ws layout: [512-B guard][9 uint8 label fields][512-B guard][pad]
  //            [packed unaries, BHW*8 floats]  (packed part optional)
  uint8_t* wsb = (uint8_t*)d_ws;
  const size_t LAB_OFF  = 512;
  const size_t need_lab = LAB_OFF + (size_t)9 * BHW + 512;
  const size_t UPK_OFF  = (need_lab + 255) & ~(size_t)255;
  const size_t need_pak = UPK_OFF + (size_t)BHW * 8 * sizeof(float);
  uint8_t* sbufs = wsb + LAB_OFF;
  float*   upk   = (float*)(wsb + UPK_OFF);

  if (ws_size >= need_pak) {
    run_two_pass<1>(unaries, upk, binaries, sample0, sbufs, acc_out, sfin,
                    ka, kb, stream);
  } else if (ws_size >= need_lab) {
    run_two_pass<0>(unaries, nullptr, binaries, sample0, sbufs, acc_out, sfin,
                    ka, kb, stream);
  } else {
    // Fallback (proven in r1/r2): per-step fused kernels, int32 ping-pong.
    int* bufA = (int*)d_ws;
    int* bufB = (int*)sfin;           // pong aliases d_out tail (safe: floats
                                      // only written at t=9, which reads bufA)
    const dim3 grid(BHW / NT), blk(NT);
    for (int t = 0; t < 10; ++t) {
      const int* sin = (t == 0) ? sample0 : ((t & 1) ? bufA : bufB);
      int* sout = (t & 1) ? bufB : bufA;
      const int mode = (t == 0) ? 0 : ((t == 9) ? 2 : 1);
      gibbs_step<<<grid, blk, 0, stream>>>(unaries, binaries, sin, sout,
                                           acc_out, sfin, ka[t], kb[t], mode);
    }
  }
}